// Round 2
// baseline (492.200 us; speedup 1.0000x reference)
//
#include <hip/hip_runtime.h>
#include <hip/hip_bf16.h>

// LSTM: B=8192 sequences, T=512, I=1, H=32, then out[b] = h_last . W_lin + b_lin.
// All inputs/outputs are FLOAT32 (per reference). Internals use packed-f16
// weights + v_dot2_f32_f16 for the recurrent matvec (f32 accumulate).
//
// Layout: 32 threads per batch (thread j owns hidden unit j -> gate rows
// j, 32+j, 64+j, 96+j). Wave = 2 batches, block = 256 threads = 8 batches.
// h broadcast via ds_swizzle (broadcast lane 2m within each 32-lane group),
// no barriers inside the T loop.

#define L2E 1.4426950408889634f

typedef _Float16 half2v __attribute__((ext_vector_type(2)));

#if defined(__has_builtin) && __has_builtin(__builtin_amdgcn_fdot2)
#define HAVE_FDOT2 1
#else
#define HAVE_FDOT2 0
#endif

__device__ __forceinline__ float dot2acc(half2v a, half2v b, float c) {
#if HAVE_FDOT2
    return __builtin_amdgcn_fdot2(a, b, c, false);
#else
    return fmaf((float)a.x, (float)b.x, fmaf((float)a.y, (float)b.y, c));
#endif
}

__global__ __launch_bounds__(256, 4) void lstm_fused(
    const float* __restrict__ x,      // [B*512] f32
    const float* __restrict__ W_ih,   // [128]   f32
    const float* __restrict__ W_hh,   // [128*32] f32
    const float* __restrict__ b_ih,   // [128]   f32
    const float* __restrict__ b_hh,   // [128]   f32
    const float* __restrict__ W_lin,  // [32]    f32
    const float* __restrict__ b_lin,  // [1]     f32
    float* __restrict__ out)          // [B]     f32
{
    __shared__ float xs[8 * 512];              // 16 KB: x for this block's 8 batches

    const int tid = threadIdx.x;
    const int j   = tid & 31;                  // hidden index 0..31
    const int bl  = tid >> 5;                  // local batch 0..7
    const long gb = (long)blockIdx.x * 8 + bl; // global batch

    // ---- stage x into LDS, coalesced float4 ----
    {
        const float4* xg = (const float4*)(x + (size_t)blockIdx.x * 8 * 512);
        #pragma unroll
        for (int i = 0; i < 4; ++i) {
            int idx = tid + i * 256;           // 1024 float4s = 4096 floats
            ((float4*)xs)[idx] = xg[idx];
        }
    }

    // ---- load + scale weights into registers ----
    // gate g: 0=i, 1=f, 2=g(tanh), 3=o. Pre-scale by log2(e) (2*log2e for the
    // tanh gate) so sigmoid(z) = rcp(1 + exp2(-acc)) and tanh(z) = 2*sig(2z)-1.
    half2v w[4][16];                           // 32 VGPRs: rows {j,32+j,64+j,96+j} of W_hh
    float  wih[4], bias[4];
    #pragma unroll
    for (int g = 0; g < 4; ++g) {
        const float s = (g == 2) ? (2.0f * L2E) : L2E;
        const int r = g * 32 + j;
        wih[g]  = W_ih[r] * s;
        bias[g] = (b_ih[r] + b_hh[r]) * s;
        #pragma unroll
        for (int m = 0; m < 16; ++m) {
            float a = W_hh[r * 32 + 2 * m    ] * s;
            float b = W_hh[r * 32 + 2 * m + 1] * s;
            half2v hv; hv.x = (_Float16)a; hv.y = (_Float16)b;
            w[g][m] = hv;
        }
    }
    __syncthreads();

    const float* xrow = &xs[bl * 512];
    float h = 0.0f, c = 0.0f;
    int   p = 0;                               // packed half2 (h[2q], h[2q+1]); h=0 -> 0

    for (int t = 0; t < 512; ++t) {
        float xt = xrow[t];

        float acc0 = fmaf(xt, wih[0], bias[0]);
        float acc1 = fmaf(xt, wih[1], bias[1]);
        float acc2 = fmaf(xt, wih[2], bias[2]);
        float acc3 = fmaf(xt, wih[3], bias[3]);

        // broadcast packed h pairs from lane 2m within each 32-lane group
        // BitMode swizzle: offset = or_mask<<5 -> every lane reads lane 2m.
        int hp[16];
        #define SWZ(m) hp[m] = __builtin_amdgcn_ds_swizzle(p, ((2 * (m)) << 5));
        SWZ(0)  SWZ(1)  SWZ(2)  SWZ(3)
        SWZ(4)  SWZ(5)  SWZ(6)  SWZ(7)
        SWZ(8)  SWZ(9)  SWZ(10) SWZ(11)
        SWZ(12) SWZ(13) SWZ(14) SWZ(15)
        #undef SWZ

        #pragma unroll
        for (int m = 0; m < 16; ++m) {
            half2v hv = __builtin_bit_cast(half2v, hp[m]);
            acc0 = dot2acc(w[0][m], hv, acc0);
            acc1 = dot2acc(w[1][m], hv, acc1);
            acc2 = dot2acc(w[2][m], hv, acc2);
            acc3 = dot2acc(w[3][m], hv, acc3);
        }

        float si = __builtin_amdgcn_rcpf(1.0f + __builtin_amdgcn_exp2f(-acc0));
        float sf = __builtin_amdgcn_rcpf(1.0f + __builtin_amdgcn_exp2f(-acc1));
        float sg = __builtin_amdgcn_rcpf(1.0f + __builtin_amdgcn_exp2f(-acc2));
        float so = __builtin_amdgcn_rcpf(1.0f + __builtin_amdgcn_exp2f(-acc3));
        float g  = fmaf(2.0f, sg, -1.0f);      // tanh(gate pre-act)
        c = fmaf(sf, c, si * g);
        float tc = __builtin_amdgcn_rcpf(1.0f + __builtin_amdgcn_exp2f(-(2.0f * L2E) * c));
        float th = fmaf(2.0f, tc, -1.0f);      // tanh(c)
        h = so * th;

        // rebuild packed pair (h[2q], h[2q+1]) shared by each lane pair
        float hn = __shfl_xor(h, 1);
        float a = (j & 1) ? hn : h;
        float b = (j & 1) ? h  : hn;
        half2v pv; pv.x = (_Float16)a; pv.y = (_Float16)b;
        p = __builtin_bit_cast(int, pv);
    }

    // ---- epilogue: out[b] = sum_j h_j * W_lin[j] + b_lin ----
    float v = h * W_lin[j];
    v += __shfl_xor(v, 1);
    v += __shfl_xor(v, 2);
    v += __shfl_xor(v, 4);
    v += __shfl_xor(v, 8);
    v += __shfl_xor(v, 16);
    if (j == 0) {
        out[gb] = v + b_lin[0];
    }
}

extern "C" void kernel_launch(void* const* d_in, const int* in_sizes, int n_in,
                              void* d_out, int out_size, void* d_ws, size_t ws_size,
                              hipStream_t stream) {
    const float* x     = (const float*)d_in[0];
    const float* W_ih  = (const float*)d_in[1];
    const float* W_hh  = (const float*)d_in[2];
    const float* b_ih  = (const float*)d_in[3];
    const float* b_hh  = (const float*)d_in[4];
    const float* W_lin = (const float*)d_in[5];
    const float* b_lin = (const float*)d_in[6];
    float* out = (float*)d_out;

    const int B = in_sizes[0] / 512;           // 8192
    dim3 grid(B / 8), block(256);
    lstm_fused<<<grid, block, 0, stream>>>(x, W_ih, W_hh, b_ih, b_hh, W_lin, b_lin, out);
}

// Round 3
// 491.765 us; speedup vs baseline: 1.0009x; 1.0009x over previous
//
#include <hip/hip_runtime.h>
#include <hip/hip_bf16.h>

// LSTM: B=8192 sequences, T=512, I=1, H=32, then out[b] = h_last . W_lin + b_lin.
// All I/O float32. Internals: packed-f16 weights + v_dot2_f32_f16 (f32 acc).
//
// Layout: 32 threads per batch (thread j owns hidden unit j -> gate rows
// j, 32+j, 64+j, 96+j). Wave = 2 batches, block = 256 threads = 8 batches.
// h broadcast via ds_swizzle (broadcast lane 2m within each 32-lane group).
//
// __launch_bounds__(256,2): VGPR cap 256 so the 64-reg weight array stays in
// ARCH VGPRs. Round-2 post-mortem: (256,4) capped at 128 -> compiler split
// weights into AGPRs (VGPR_Count=56 + ~64 acc) -> +64 v_accvgpr_read per
// step -> 464 issue-cyc/wave-step instead of ~245.

#define L2E 1.4426950408889634f

typedef _Float16 half2v __attribute__((ext_vector_type(2)));

__device__ __forceinline__ float dot2acc(half2v a, half2v b, float c) {
    return __builtin_amdgcn_fdot2(a, b, c, false);
}

__global__ __launch_bounds__(256, 2) void lstm_fused(
    const float* __restrict__ x,      // [B*512] f32
    const float* __restrict__ W_ih,   // [128]   f32
    const float* __restrict__ W_hh,   // [128*32] f32
    const float* __restrict__ b_ih,   // [128]   f32
    const float* __restrict__ b_hh,   // [128]   f32
    const float* __restrict__ W_lin,  // [32]    f32
    const float* __restrict__ b_lin,  // [1]     f32
    float* __restrict__ out)          // [B]     f32
{
    __shared__ float xs[8 * 512];              // 16 KB: x for this block's 8 batches

    const int tid = threadIdx.x;
    const int j   = tid & 31;                  // hidden index 0..31
    const int bl  = tid >> 5;                  // local batch 0..7
    const long gb = (long)blockIdx.x * 8 + bl; // global batch

    // ---- stage x into LDS, coalesced float4 ----
    {
        const float4* xg = (const float4*)(x + (size_t)blockIdx.x * 8 * 512);
        #pragma unroll
        for (int i = 0; i < 4; ++i) {
            int idx = tid + i * 256;           // 1024 float4s = 4096 floats
            ((float4*)xs)[idx] = xg[idx];
        }
    }

    // ---- load + scale weights into registers ----
    // gate g: 0=i, 1=f, 2=g(tanh), 3=o. Pre-scale by log2(e) (2*log2e for the
    // tanh gate) so sigmoid(z) = rcp(1 + exp2(-acc)) and tanh(z) = 2*sig(2z)-1.
    half2v w[4][16];                           // 64 VGPRs: rows {j,32+j,64+j,96+j} of W_hh
    float  wih[4], bias[4];
    #pragma unroll
    for (int g = 0; g < 4; ++g) {
        const float s = (g == 2) ? (2.0f * L2E) : L2E;
        const int r = g * 32 + j;
        wih[g]  = W_ih[r] * s;
        bias[g] = (b_ih[r] + b_hh[r]) * s;
        #pragma unroll
        for (int m = 0; m < 16; ++m) {
            float a = W_hh[r * 32 + 2 * m    ] * s;
            float b = W_hh[r * 32 + 2 * m + 1] * s;
            half2v hv; hv.x = (_Float16)a; hv.y = (_Float16)b;
            w[g][m] = hv;
        }
    }
    __syncthreads();

    const float* xrow = &xs[bl * 512];
    float h = 0.0f, c = 0.0f;
    int   p = 0;                               // packed half2 (h[2q], h[2q+1]); h=0 -> 0

    #pragma unroll 4
    for (int t = 0; t < 512; ++t) {
        float xt = xrow[t];

        float acc0 = fmaf(xt, wih[0], bias[0]);
        float acc1 = fmaf(xt, wih[1], bias[1]);
        float acc2 = fmaf(xt, wih[2], bias[2]);
        float acc3 = fmaf(xt, wih[3], bias[3]);

        // broadcast packed h pairs from lane 2m within each 32-lane group
        // BitMode swizzle: offset = or_mask<<5 -> every lane reads lane 2m.
        int hp[16];
        #define SWZ(m) hp[m] = __builtin_amdgcn_ds_swizzle(p, ((2 * (m)) << 5));
        SWZ(0)  SWZ(1)  SWZ(2)  SWZ(3)
        SWZ(4)  SWZ(5)  SWZ(6)  SWZ(7)
        SWZ(8)  SWZ(9)  SWZ(10) SWZ(11)
        SWZ(12) SWZ(13) SWZ(14) SWZ(15)
        #undef SWZ

        #pragma unroll
        for (int m = 0; m < 16; ++m) {
            half2v hv = __builtin_bit_cast(half2v, hp[m]);
            acc0 = dot2acc(w[0][m], hv, acc0);
            acc1 = dot2acc(w[1][m], hv, acc1);
            acc2 = dot2acc(w[2][m], hv, acc2);
            acc3 = dot2acc(w[3][m], hv, acc3);
        }

        float si = __builtin_amdgcn_rcpf(1.0f + __builtin_amdgcn_exp2f(-acc0));
        float sf = __builtin_amdgcn_rcpf(1.0f + __builtin_amdgcn_exp2f(-acc1));
        float sg = __builtin_amdgcn_rcpf(1.0f + __builtin_amdgcn_exp2f(-acc2));
        float so = __builtin_amdgcn_rcpf(1.0f + __builtin_amdgcn_exp2f(-acc3));
        float g  = fmaf(2.0f, sg, -1.0f);      // tanh(gate pre-act)
        c = fmaf(sf, c, si * g);
        float tc = __builtin_amdgcn_rcpf(1.0f + __builtin_amdgcn_exp2f(-(2.0f * L2E) * c));
        float th = fmaf(2.0f, tc, -1.0f);      // tanh(c)
        h = so * th;

        // rebuild packed pair; only EVEN lanes are ever read by the swizzle,
        // so (h, neighbor) order is correct where it matters — no cndmasks.
        float hn = __shfl_xor(h, 1);
        p = __builtin_bit_cast(int, __builtin_amdgcn_cvt_pkrtz(h, hn));
    }

    // ---- epilogue: out[b] = sum_j h_j * W_lin[j] + b_lin ----
    float v = h * W_lin[j];
    v += __shfl_xor(v, 1);
    v += __shfl_xor(v, 2);
    v += __shfl_xor(v, 4);
    v += __shfl_xor(v, 8);
    v += __shfl_xor(v, 16);
    if (j == 0) {
        out[gb] = v + b_lin[0];
    }
}

extern "C" void kernel_launch(void* const* d_in, const int* in_sizes, int n_in,
                              void* d_out, int out_size, void* d_ws, size_t ws_size,
                              hipStream_t stream) {
    const float* x     = (const float*)d_in[0];
    const float* W_ih  = (const float*)d_in[1];
    const float* W_hh  = (const float*)d_in[2];
    const float* b_ih  = (const float*)d_in[3];
    const float* b_hh  = (const float*)d_in[4];
    const float* W_lin = (const float*)d_in[5];
    const float* b_lin = (const float*)d_in[6];
    float* out = (float*)d_out;

    const int B = in_sizes[0] / 512;           // 8192
    dim3 grid(B / 8), block(256);
    lstm_fused<<<grid, block, 0, stream>>>(x, W_ih, W_hh, b_ih, b_hh, W_lin, b_lin, out);
}

// Round 4
// 412.860 us; speedup vs baseline: 1.1922x; 1.1911x over previous
//
#include <hip/hip_runtime.h>

// LSTM B=8192, T=512, I=1, H=32; out[b] = h_T . W_lin + b_lin.  All I/O f32.
//
// MFMA formulation: one wave per 16 batches (512 blocks x 64 threads).
// Per step: gates[128 x 16b] = W_hh[128x32] @ h[32 x 16b]  via 8x
// mfma_f32_16x16x32_f16 with A = W_hh rows (M=gate), B = h (N=batch).
//   A-frag: lane holds A[m=lane&15][k=quad*8+j]  -> gate row g=16t+(lane&15)
//   B-frag: lane holds B[k=quad*8+j][n=lane&15]  -> batch n, hiddens quad*8..+7
//   D:      col=lane&15 (batch), row=quad*4+reg (+16*tile) (gate)
// => lane (quad q, col) accumulates ALL 4 gate types for hiddens
//    {4q..4q+3, 16+4q..16+4q+3} of batch col: activations are lane-local.
// h -> next B-frag via in-wave LDS exchange (4 ds_write_b32 + ds_read_b128).
// Gate pre-acts pre-scaled by log2e (2*log2e for tanh gate) so
// sigmoid(z)=rcp(1+exp2(-acc)), tanh(z)=2*rcp(1+exp2(-acc))-1.

#define L2E 1.4426950408889634f

typedef _Float16 f16x8 __attribute__((ext_vector_type(8)));
typedef _Float16 f16x2 __attribute__((ext_vector_type(2)));
typedef float    f32x4 __attribute__((ext_vector_type(4)));

__global__ __launch_bounds__(64, 1) void lstm_mfma(
    const float* __restrict__ x,      // [B*512]
    const float* __restrict__ W_ih,   // [128]
    const float* __restrict__ W_hh,   // [128*32]
    const float* __restrict__ b_ih,   // [128]
    const float* __restrict__ b_hh,   // [128]
    const float* __restrict__ W_lin,  // [32]
    const float* __restrict__ b_lin,  // [1]
    float* __restrict__ out)          // [B]
{
    __shared__ float xs[512 * 17];                    // x transposed [t][b], stride 17 (34816 B)
    __shared__ __align__(16) unsigned int hl[16 * 20]; // h as half2 pairs, col-stride 20 (1280 B)

    const int lane = threadIdx.x;      // 0..63
    const int col  = lane & 15;        // batch within group
    const int quad = lane >> 4;        // 0..3
    const int base = blockIdx.x * 16;  // global batch base

    // ---- stage x[base..base+15][0..511] into LDS transposed ----
    {
        const float4* xg = (const float4*)(x + (size_t)base * 512);
        #pragma unroll
        for (int it = 0; it < 32; ++it) {
            int idx = it * 64 + lane;          // 0..2047 float4s
            int b   = idx >> 7;                // 0..15
            int t4  = idx & 127;
            float4 v = xg[idx];
            int t0 = t4 * 4;
            xs[(t0 + 0) * 17 + b] = v.x;
            xs[(t0 + 1) * 17 + b] = v.y;
            xs[(t0 + 2) * 17 + b] = v.z;
            xs[(t0 + 3) * 17 + b] = v.w;
        }
    }

    // ---- A-fragments: W_hh rows, pre-scaled, f16 ----
    // tile t covers gate rows 16t..16t+15; type = t>>1 (0:i 1:f 2:g 3:o)
    f16x8 wA[8];
    #pragma unroll
    for (int t = 0; t < 8; ++t) {
        const float s = ((t >> 1) == 2) ? (2.0f * L2E) : L2E;
        const int g = 16 * t + col;
        #pragma unroll
        for (int j = 0; j < 8; ++j)
            wA[t][j] = (_Float16)(W_hh[g * 32 + quad * 8 + j] * s);
    }

    // ---- C-init constants: D-layout row = quad*4 + r (+16t) ----
    float wih[8][4], bia[8][4];
    #pragma unroll
    for (int t = 0; t < 8; ++t) {
        const float s = ((t >> 1) == 2) ? (2.0f * L2E) : L2E;
        #pragma unroll
        for (int r = 0; r < 4; ++r) {
            const int g = 16 * t + quad * 4 + r;
            wih[t][r] = W_ih[g] * s;
            bia[t][r] = (b_ih[g] + b_hh[g]) * s;
        }
    }

    // W_lin for this lane's hiddens: hid(e) = (e>>2)*16 + quad*4 + (e&3)
    float wl[8];
    #pragma unroll
    for (int e = 0; e < 8; ++e)
        wl[e] = W_lin[(e >> 2) * 16 + quad * 4 + (e & 3)];

    __syncthreads();

    f16x8 bfrag = {};                  // h = 0
    float c[8] = {0, 0, 0, 0, 0, 0, 0, 0};
    float h[8];

    #pragma unroll 1
    for (int t = 0; t < 512; ++t) {
        float xt = xs[t * 17 + col];

        f32x4 acc[8];
        #pragma unroll
        for (int tt = 0; tt < 8; ++tt)
            #pragma unroll
            for (int r = 0; r < 4; ++r)
                acc[tt][r] = fmaf(xt, wih[tt][r], bia[tt][r]);

        #pragma unroll
        for (int tt = 0; tt < 8; ++tt)
            acc[tt] = __builtin_amdgcn_mfma_f32_16x16x32_f16(wA[tt], bfrag, acc[tt], 0, 0, 0);

        // activations: e -> hid = (e>>2)*16 + quad*4 + (e&3)
        #pragma unroll
        for (int e = 0; e < 8; ++e) {
            const int lo = e >> 2, r = e & 3;
            float ia = acc[0 + lo][r];
            float fa = acc[2 + lo][r];
            float ga = acc[4 + lo][r];
            float oa = acc[6 + lo][r];
            float si = __builtin_amdgcn_rcpf(1.0f + __builtin_amdgcn_exp2f(-ia));
            float sf = __builtin_amdgcn_rcpf(1.0f + __builtin_amdgcn_exp2f(-fa));
            float sg = __builtin_amdgcn_rcpf(1.0f + __builtin_amdgcn_exp2f(-ga));
            float so = __builtin_amdgcn_rcpf(1.0f + __builtin_amdgcn_exp2f(-oa));
            float gg = fmaf(2.0f, sg, -1.0f);          // tanh(gate)
            c[e] = fmaf(sf, c[e], si * gg);
            float tc = __builtin_amdgcn_rcpf(1.0f + __builtin_amdgcn_exp2f(-(2.0f * L2E) * c[e]));
            h[e] = so * fmaf(2.0f, tc, -1.0f);          // o * tanh(c)
        }

        // exchange h -> B-frag. lane's h pairs: low {2q, 2q+1}, high {8+2q, 9+2q}
        unsigned int* hc = &hl[col * 20];
        hc[2 * quad    ] = __builtin_bit_cast(unsigned int, __builtin_amdgcn_cvt_pkrtz(h[0], h[1]));
        hc[2 * quad + 1] = __builtin_bit_cast(unsigned int, __builtin_amdgcn_cvt_pkrtz(h[2], h[3]));
        hc[8 + 2 * quad    ] = __builtin_bit_cast(unsigned int, __builtin_amdgcn_cvt_pkrtz(h[4], h[5]));
        hc[8 + 2 * quad + 1] = __builtin_bit_cast(unsigned int, __builtin_amdgcn_cvt_pkrtz(h[6], h[7]));
        __syncthreads();                                // single-wave block: waitcnt + barrier
        uint4 bv = *(const uint4*)&hl[col * 20 + quad * 4]; // pairs quad*4..+3 = k quad*8..+7
        bfrag = __builtin_bit_cast(f16x8, bv);
    }

    // ---- epilogue ----
    float v = 0.0f;
    #pragma unroll
    for (int e = 0; e < 8; ++e) v = fmaf(h[e], wl[e], v);
    v += __shfl_xor(v, 16);
    v += __shfl_xor(v, 32);
    if (lane < 16) out[base + col] = v + b_lin[0];
}

extern "C" void kernel_launch(void* const* d_in, const int* in_sizes, int n_in,
                              void* d_out, int out_size, void* d_ws, size_t ws_size,
                              hipStream_t stream) {
    const float* x     = (const float*)d_in[0];
    const float* W_ih  = (const float*)d_in[1];
    const float* W_hh  = (const float*)d_in[2];
    const float* b_ih  = (const float*)d_in[3];
    const float* b_hh  = (const float*)d_in[4];
    const float* W_lin = (const float*)d_in[5];
    const float* b_lin = (const float*)d_in[6];
    float* out = (float*)d_out;

    const int B = in_sizes[0] / 512;   // 8192
    dim3 grid(B / 16), block(64);
    lstm_mfma<<<grid, block, 0, stream>>>(x, W_ih, W_hh, b_ih, b_hh, W_lin, b_lin, out);
}

// Round 5
// 349.272 us; speedup vs baseline: 1.4092x; 1.1821x over previous
//
#include <hip/hip_runtime.h>

// LSTM B=8192, T=512, I=1, H=32; out[b] = h_T . W_lin + b_lin.  All I/O f32.
//
// MFMA formulation, 2 waves per 16-batch group (512 blocks x 128 threads).
// Wave w (w=0,1) owns hidden half 16w..16w+15: MFMA tiles {w, 2+w, 4+w, 6+w}
// (tile 2T+w = gate type T, hiddens 16w..16w+15). Per wave-step:
//   4x mfma_f32_16x16x32_f16, A = W_hh rows (M=gate), B = h (N=batch):
//     A-frag: lane(quad,col) holds A[m=col][k=quad*8+j]
//     D:      col=batch, row=quad*4+r -> gate type T, hidden j=16w+4quad+r
//   -> each lane updates c,h for 4 hiddens of ONE batch (lane-local activations).
// h exchange via double-buffered LDS (pairs p=j/2 at buf[col*20+p]), ONE
// barrier per step. Round-4 lesson: wall = 512 * chain-length (waves are
// independent; occupancy can't hide a per-wave serial chain) -> this split
// halves the per-wave issue component of the chain.
// Pre-acts pre-scaled by log2e (2*log2e for tanh gate):
//   sigmoid(z)=rcp(1+exp2(-acc)), tanh(z)=2*rcp(1+exp2(-2*L2E*z'))-1.

#define L2E 1.4426950408889634f

typedef _Float16 f16x8 __attribute__((ext_vector_type(8)));
typedef float    f32x4 __attribute__((ext_vector_type(4)));

__global__ __launch_bounds__(128, 2) void lstm_mfma2(
    const float* __restrict__ x,      // [B*512]
    const float* __restrict__ W_ih,   // [128]
    const float* __restrict__ W_hh,   // [128*32]
    const float* __restrict__ b_ih,   // [128]
    const float* __restrict__ b_hh,   // [128]
    const float* __restrict__ W_lin,  // [32]
    const float* __restrict__ b_lin,  // [1]
    float* __restrict__ out)          // [B]
{
    __shared__ float xs[512 * 17];                       // x transposed [t][b], stride 17
    __shared__ __align__(16) unsigned int hb[2][16 * 20]; // h pair buffers, col-stride 20
    __shared__ float ps[32];                              // epilogue partials

    const int tid  = threadIdx.x;
    const int wv   = tid >> 6;         // wave 0/1 = hidden half
    const int lane = tid & 63;
    const int col  = lane & 15;        // batch within group
    const int quad = lane >> 4;        // 0..3
    const int base = blockIdx.x * 16;  // global batch base

    // ---- stage x[base..base+15][0..511] into LDS transposed ----
    {
        const float4* xg = (const float4*)(x + (size_t)base * 512);
        #pragma unroll
        for (int it = 0; it < 16; ++it) {
            float4 v = xg[it * 128 + tid];       // batch=it, times 4*tid..4*tid+3
            int t0 = tid * 4;
            xs[(t0 + 0) * 17 + it] = v.x;
            xs[(t0 + 1) * 17 + it] = v.y;
            xs[(t0 + 2) * 17 + it] = v.z;
            xs[(t0 + 3) * 17 + it] = v.w;
        }
    }

    // ---- per-wave weights: tiles 2T+wv, T=0..3 (gate types i,f,g,o) ----
    f16x8 wA[4];
    float wih[4][4], bia[4][4];
    #pragma unroll
    for (int T = 0; T < 4; ++T) {
        const int tile = 2 * T + wv;
        const float s = (T == 2) ? (2.0f * L2E) : L2E;
        const int ga = 16 * tile + col;          // A-frag row
        #pragma unroll
        for (int j = 0; j < 8; ++j)
            wA[T][j] = (_Float16)(W_hh[ga * 32 + quad * 8 + j] * s);
        #pragma unroll
        for (int r = 0; r < 4; ++r) {
            const int g = 16 * tile + quad * 4 + r;   // D row
            wih[T][r] = W_ih[g] * s;
            bia[T][r] = (b_ih[g] + b_hh[g]) * s;
        }
    }
    float wl[4];
    #pragma unroll
    for (int r = 0; r < 4; ++r)
        wl[r] = W_lin[16 * wv + 4 * quad + r];

    __syncthreads();

    float c[4] = {0, 0, 0, 0};
    float h[4];

    // one LSTM step; writes h pairs into buf, barriers, returns next B-frag
    auto do_step = [&](int t, f16x8 bfrag, unsigned int* buf) -> f16x8 {
        float xt = xs[t * 17 + col];

        f32x4 acc[4];
        #pragma unroll
        for (int T = 0; T < 4; ++T)
            #pragma unroll
            for (int r = 0; r < 4; ++r)
                acc[T][r] = fmaf(xt, wih[T][r], bia[T][r]);

        #pragma unroll
        for (int T = 0; T < 4; ++T)
            acc[T] = __builtin_amdgcn_mfma_f32_16x16x32_f16(wA[T], bfrag, acc[T], 0, 0, 0);

        #pragma unroll
        for (int r = 0; r < 4; ++r) {
            float si = __builtin_amdgcn_rcpf(1.0f + __builtin_amdgcn_exp2f(-acc[0][r]));
            float sf = __builtin_amdgcn_rcpf(1.0f + __builtin_amdgcn_exp2f(-acc[1][r]));
            float sg = __builtin_amdgcn_rcpf(1.0f + __builtin_amdgcn_exp2f(-acc[2][r]));
            float so = __builtin_amdgcn_rcpf(1.0f + __builtin_amdgcn_exp2f(-acc[3][r]));
            float gg = fmaf(2.0f, sg, -1.0f);            // tanh(gate)
            c[r] = fmaf(sf, c[r], si * gg);
            float tc = __builtin_amdgcn_rcpf(1.0f + __builtin_amdgcn_exp2f(-(2.0f * L2E) * c[r]));
            h[r] = so * fmaf(2.0f, tc, -1.0f);           // o * tanh(c)
        }

        // write this wave's 4 hiddens as 2 half2 pairs: p = 8*wv + 2*quad (+1)
        uint2 pk;
        pk.x = __builtin_bit_cast(unsigned int, __builtin_amdgcn_cvt_pkrtz(h[0], h[1]));
        pk.y = __builtin_bit_cast(unsigned int, __builtin_amdgcn_cvt_pkrtz(h[2], h[3]));
        *(uint2*)&buf[col * 20 + 8 * wv + 2 * quad] = pk;
        __syncthreads();
        // B-frag: pairs quad*4..+3 of batch col = k quad*8..quad*8+7
        uint4 bv = *(const uint4*)&buf[col * 20 + quad * 4];
        return __builtin_bit_cast(f16x8, bv);
    };

    f16x8 bfrag = {};                  // h0 = 0
    for (int t = 0; t < 512; t += 2) {
        bfrag = do_step(t,     bfrag, hb[0]);
        bfrag = do_step(t + 1, bfrag, hb[1]);
    }

    // ---- epilogue: out[b] = sum_j h_j * W_lin[j] + b_lin ----
    float v = 0.0f;
    #pragma unroll
    for (int r = 0; r < 4; ++r) v = fmaf(h[r], wl[r], v);
    v += __shfl_xor(v, 16);            // combine quads
    v += __shfl_xor(v, 32);
    if (lane < 16) ps[wv * 16 + col] = v;
    __syncthreads();
    if (tid < 16) out[base + tid] = ps[tid] + ps[16 + tid] + b_lin[0];
}

extern "C" void kernel_launch(void* const* d_in, const int* in_sizes, int n_in,
                              void* d_out, int out_size, void* d_ws, size_t ws_size,
                              hipStream_t stream) {
    const float* x     = (const float*)d_in[0];
    const float* W_ih  = (const float*)d_in[1];
    const float* W_hh  = (const float*)d_in[2];
    const float* b_ih  = (const float*)d_in[3];
    const float* b_hh  = (const float*)d_in[4];
    const float* W_lin = (const float*)d_in[5];
    const float* b_lin = (const float*)d_in[6];
    float* out = (float*)d_out;

    const int B = in_sizes[0] / 512;   // 8192
    dim3 grid(B / 16), block(128);
    lstm_mfma2<<<grid, block, 0, stream>>>(x, W_ih, W_hh, b_ih, b_hh, W_lin, b_lin, out);
}

// Round 6
// 348.610 us; speedup vs baseline: 1.4119x; 1.0019x over previous
//
#include <hip/hip_runtime.h>

// LSTM B=8192, T=512, I=1, H=32; out[b] = h_T . W_lin + b_lin.  All I/O f32.
//
// MFMA formulation, 2 waves per 16-batch group (512 blocks x 128 threads).
// Wave w owns hidden half 16w..16w+15: MFMA tiles {w, 2+w, 4+w, 6+w}.
//   A-frag: lane(quad,col) holds W_hh[m=col][k=quad*8+j] (tile-relative)
//   D:      col=batch, row=quad*4+r -> gate type T, hidden 16w+4quad+r
// Each lane updates c,h for 4 hiddens of ONE batch (lane-local activations).
// h exchange via double-buffered LDS, ONE barrier/step.
//
// R5 post-mortem: chain = 1392 cyc/step = ~600 busy (trans pipe is ~8-wide:
// 40 trans x 8 = 320) + ~780 exposed latency. Occupancy is pinned at 1
// wave/SIMD (1024 waves max for this split) -> only lever is the chain:
//  - prefetch x_{t+1} + compute next C-init BETWEEN h-write and barrier
//  - split h-write into 2x b32 issued as soon as each half is ready
//  - batch exp2s before rcps for trans-latency overlap
// Pre-acts pre-scaled by log2e (2*log2e for tanh gate):
//   sigmoid(z)=rcp(1+exp2(-acc)), tanh(z)=2*rcp(1+exp2(-2*L2E*z'))-1.

#define L2E 1.4426950408889634f

typedef _Float16 f16x8 __attribute__((ext_vector_type(8)));
typedef float    f32x4 __attribute__((ext_vector_type(4)));

__global__ __launch_bounds__(128, 2) void lstm_mfma3(
    const float* __restrict__ x,      // [B*512]
    const float* __restrict__ W_ih,   // [128]
    const float* __restrict__ W_hh,   // [128*32]
    const float* __restrict__ b_ih,   // [128]
    const float* __restrict__ b_hh,   // [128]
    const float* __restrict__ W_lin,  // [32]
    const float* __restrict__ b_lin,  // [1]
    float* __restrict__ out)          // [B]
{
    __shared__ float xs[512 * 17];                        // x transposed [t][b], stride 17
    __shared__ __align__(16) unsigned int hb[2][16 * 20]; // h pair buffers, col-stride 20
    __shared__ float ps[32];                              // epilogue partials

    const int tid  = threadIdx.x;
    const int wv   = tid >> 6;         // wave 0/1 = hidden half
    const int lane = tid & 63;
    const int col  = lane & 15;        // batch within group
    const int quad = lane >> 4;        // 0..3
    const int base = blockIdx.x * 16;  // global batch base

    // ---- stage x[base..base+15][0..511] into LDS transposed ----
    {
        const float4* xg = (const float4*)(x + (size_t)base * 512);
        #pragma unroll
        for (int it = 0; it < 16; ++it) {
            float4 v = xg[it * 128 + tid];       // batch=it, times 4*tid..4*tid+3
            int t0 = tid * 4;
            xs[(t0 + 0) * 17 + it] = v.x;
            xs[(t0 + 1) * 17 + it] = v.y;
            xs[(t0 + 2) * 17 + it] = v.z;
            xs[(t0 + 3) * 17 + it] = v.w;
        }
    }

    // ---- per-wave weights: tiles 2T+wv, T=0..3 (gate types i,f,g,o) ----
    f16x8 wA[4];
    float wih[4][4], bia[4][4];
    #pragma unroll
    for (int T = 0; T < 4; ++T) {
        const int tile = 2 * T + wv;
        const float s = (T == 2) ? (2.0f * L2E) : L2E;
        const int ga = 16 * tile + col;          // A-frag row
        #pragma unroll
        for (int j = 0; j < 8; ++j)
            wA[T][j] = (_Float16)(W_hh[ga * 32 + quad * 8 + j] * s);
        #pragma unroll
        for (int r = 0; r < 4; ++r) {
            const int g = 16 * tile + quad * 4 + r;   // D row
            wih[T][r] = W_ih[g] * s;
            bia[T][r] = (b_ih[g] + b_hh[g]) * s;
        }
    }
    float wl[4];
    #pragma unroll
    for (int r = 0; r < 4; ++r)
        wl[r] = W_lin[16 * wv + 4 * quad + r];

    __syncthreads();

    float c[4] = {0, 0, 0, 0};
    float h[4];
    f16x8 bfrag = {};                  // h0 = 0

    // C-init for t=0 (precomputed; thereafter computed pre-barrier each step)
    f32x4 ci[4];
    {
        float xt = xs[col];
        #pragma unroll
        for (int T = 0; T < 4; ++T)
            #pragma unroll
            for (int r = 0; r < 4; ++r)
                ci[T][r] = fmaf(xt, wih[T][r], bia[T][r]);
    }

    #pragma unroll 2
    for (int t = 0; t < 512; ++t) {
        unsigned int* buf = hb[t & 1];

        f32x4 acc[4];
        #pragma unroll
        for (int T = 0; T < 4; ++T)
            acc[T] = __builtin_amdgcn_mfma_f32_16x16x32_f16(wA[T], bfrag, ci[T], 0, 0, 0);

        // prefetch next x (independent of bfrag/h; overlaps MFMA + activations)
        float xt1 = xs[((t + 1) & 511) * 17 + col];

        // activations in 2 halves; write each half's pair ASAP
        #pragma unroll
        for (int half = 0; half < 2; ++half) {
            const int r0 = 2 * half, r1 = r0 + 1;
            // batch the 8 exps (trans latencies overlap)
            float ei0 = __builtin_amdgcn_exp2f(-acc[0][r0]);
            float ef0 = __builtin_amdgcn_exp2f(-acc[1][r0]);
            float eg0 = __builtin_amdgcn_exp2f(-acc[2][r0]);
            float eo0 = __builtin_amdgcn_exp2f(-acc[3][r0]);
            float ei1 = __builtin_amdgcn_exp2f(-acc[0][r1]);
            float ef1 = __builtin_amdgcn_exp2f(-acc[1][r1]);
            float eg1 = __builtin_amdgcn_exp2f(-acc[2][r1]);
            float eo1 = __builtin_amdgcn_exp2f(-acc[3][r1]);
            float si0 = __builtin_amdgcn_rcpf(1.0f + ei0);
            float sf0 = __builtin_amdgcn_rcpf(1.0f + ef0);
            float sg0 = __builtin_amdgcn_rcpf(1.0f + eg0);
            float so0 = __builtin_amdgcn_rcpf(1.0f + eo0);
            float si1 = __builtin_amdgcn_rcpf(1.0f + ei1);
            float sf1 = __builtin_amdgcn_rcpf(1.0f + ef1);
            float sg1 = __builtin_amdgcn_rcpf(1.0f + eg1);
            float so1 = __builtin_amdgcn_rcpf(1.0f + eo1);
            float gg0 = fmaf(2.0f, sg0, -1.0f);
            float gg1 = fmaf(2.0f, sg1, -1.0f);
            c[r0] = fmaf(sf0, c[r0], si0 * gg0);
            c[r1] = fmaf(sf1, c[r1], si1 * gg1);
            float tc0 = __builtin_amdgcn_rcpf(1.0f + __builtin_amdgcn_exp2f(c[r0] * (-2.0f * L2E)));
            float tc1 = __builtin_amdgcn_rcpf(1.0f + __builtin_amdgcn_exp2f(c[r1] * (-2.0f * L2E)));
            h[r0] = so0 * fmaf(2.0f, tc0, -1.0f);
            h[r1] = so1 * fmaf(2.0f, tc1, -1.0f);
            // pair p = 8*wv + 2*quad + half covers hiddens 16wv+4quad+{2*half, 2*half+1}
            buf[col * 20 + 8 * wv + 2 * quad + half] =
                __builtin_bit_cast(unsigned int, __builtin_amdgcn_cvt_pkrtz(h[r0], h[r1]));
        }

        // next step's C-init while the h-write drains (pre-barrier slack)
        #pragma unroll
        for (int T = 0; T < 4; ++T)
            #pragma unroll
            for (int r = 0; r < 4; ++r)
                ci[T][r] = fmaf(xt1, wih[T][r], bia[T][r]);

        __syncthreads();
        // B-frag: pairs quad*4..+3 of batch col = k quad*8..quad*8+7
        uint4 bv = *(const uint4*)&buf[col * 20 + quad * 4];
        bfrag = __builtin_bit_cast(f16x8, bv);
    }

    // ---- epilogue: out[b] = sum_j h_j * W_lin[j] + b_lin ----
    float v = 0.0f;
    #pragma unroll
    for (int r = 0; r < 4; ++r) v = fmaf(h[r], wl[r], v);
    v += __shfl_xor(v, 16);            // combine quads
    v += __shfl_xor(v, 32);
    if (lane < 16) ps[wv * 16 + col] = v;
    __syncthreads();
    if (tid < 16) out[base + tid] = ps[tid] + ps[16 + tid] + b_lin[0];
}

extern "C" void kernel_launch(void* const* d_in, const int* in_sizes, int n_in,
                              void* d_out, int out_size, void* d_ws, size_t ws_size,
                              hipStream_t stream) {
    const float* x     = (const float*)d_in[0];
    const float* W_ih  = (const float*)d_in[1];
    const float* W_hh  = (const float*)d_in[2];
    const float* b_ih  = (const float*)d_in[3];
    const float* b_hh  = (const float*)d_in[4];
    const float* W_lin = (const float*)d_in[5];
    const float* b_lin = (const float*)d_in[6];
    float* out = (float*)d_out;

    const int B = in_sizes[0] / 512;   // 8192
    dim3 grid(B / 16), block(128);
    lstm_mfma3<<<grid, block, 0, stream>>>(x, W_ih, W_hh, b_ih, b_hh, W_lin, b_lin, out);
}

// Round 7
// 262.355 us; speedup vs baseline: 1.8761x; 1.3288x over previous
//
#include <hip/hip_runtime.h>

// LSTM B=8192, T=512, I=1, H=32; out[b] = h_T . W_lin + b_lin.  All I/O f32.
//
// MFMA formulation, 4 waves per 16-batch group (512 blocks x 256 threads).
// wv = tid>>6; half = wv>>1 (hidden half), rsel = wv&1 (r-pair).
// Waves (half,0) and (half,1) BOTH compute tiles {half,2+half,4+half,6+half}
// (tile 2T+half = gate type T, hiddens [16half,16half+16)) — MFMA duplicated
// 2x — but activate complementary r-pairs: rsel=0 -> D rows 4q+{0,1},
// rsel=1 -> 4q+{2,3}. Trick: rsel=1 waves load A-rows permuted by col^2
// (row-permuting A permutes D rows identically), so every wave's owned
// gates land in acc slots {0,1} -> compile-time indices.
//   lane(quad,col) owns hiddens j0=16half+4quad+2rsel, j0+1 of batch col.
// R6 post-mortem: 2-wave split pins 1024 waves = 1 wave/SIMD; chain latency
// (~850cyc/step) is unhidable; trans (~9.6cyc/wave64 issue) is 60% of busy.
// This split: 2048 waves = 2/SIMD (independent chains interleave) and trans
// per wave 40->20. MFMA duplication rides the idle matrix pipe (4.7% busy).
// Pre-acts pre-scaled by log2e (2*log2e for tanh gate):
//   sigmoid(z)=rcp(1+exp2(-acc)), tanh(z)=2*rcp(1+exp2(-2*L2E*z'))-1.

#define L2E 1.4426950408889634f

typedef _Float16 f16x8 __attribute__((ext_vector_type(8)));
typedef float    f32x4 __attribute__((ext_vector_type(4)));

__global__ __launch_bounds__(256, 2) void lstm_mfma4(
    const float* __restrict__ x,      // [B*512]
    const float* __restrict__ W_ih,   // [128]
    const float* __restrict__ W_hh,   // [128*32]
    const float* __restrict__ b_ih,   // [128]
    const float* __restrict__ b_hh,   // [128]
    const float* __restrict__ W_lin,  // [32]
    const float* __restrict__ b_lin,  // [1]
    float* __restrict__ out)          // [B]
{
    __shared__ float xs[512 * 17];                        // x transposed [t][b], stride 17
    __shared__ __align__(16) unsigned int hb[2][16 * 20]; // h pair buffers, col-stride 20
    __shared__ float ps[64];                              // epilogue partials

    const int tid  = threadIdx.x;
    const int wv   = tid >> 6;         // 0..3
    const int half = wv >> 1;          // hidden half 0/1
    const int rsel = wv & 1;           // r-pair select
    const int lane = tid & 63;
    const int col  = lane & 15;        // batch within group
    const int quad = lane >> 4;        // 0..3
    const int base = blockIdx.x * 16;  // global batch base

    // ---- stage x[base..base+15][0..511] into LDS transposed ----
    {
        const float4* xg = (const float4*)(x + (size_t)base * 512);
        #pragma unroll
        for (int it = 0; it < 8; ++it) {
            int idx = it * 256 + tid;          // 0..2047 float4s
            float4 v = xg[idx];
            int b  = idx >> 7;                 // batch 0..15
            int t0 = (idx & 127) * 4;
            xs[(t0 + 0) * 17 + b] = v.x;
            xs[(t0 + 1) * 17 + b] = v.y;
            xs[(t0 + 2) * 17 + b] = v.z;
            xs[(t0 + 3) * 17 + b] = v.w;
        }
    }

    // ---- per-wave weights: tiles 2T+half, A-rows permuted by ^(rsel<<1) ----
    f16x8 wA[4];
    float wih2[4][2], bia2[4][2];
    #pragma unroll
    for (int T = 0; T < 4; ++T) {
        const int tile = 2 * T + half;
        const float s = (T == 2) ? (2.0f * L2E) : L2E;
        const int ga = 16 * tile + (col ^ (rsel << 1));   // permuted A row
        #pragma unroll
        for (int j = 0; j < 8; ++j)
            wA[T][j] = (_Float16)(W_hh[ga * 32 + quad * 8 + j] * s);
        #pragma unroll
        for (int r = 0; r < 2; ++r) {
            const int g = 16 * tile + quad * 4 + 2 * rsel + r;  // owned D row's gate
            wih2[T][r] = W_ih[g] * s;
            bia2[T][r] = (b_ih[g] + b_hh[g]) * s;
        }
    }
    const int j0 = 16 * half + 4 * quad + 2 * rsel;  // first owned hidden
    const float wl0 = W_lin[j0], wl1 = W_lin[j0 + 1];

    __syncthreads();

    float c0 = 0.0f, c1 = 0.0f, h0 = 0.0f, h1 = 0.0f;
    f16x8 bfrag = {};                  // h = 0
    // C-operands: slots {0,1} live (owned gates), slots {2,3} stay zero forever
    f32x4 cq[4] = {{0,0,0,0}, {0,0,0,0}, {0,0,0,0}, {0,0,0,0}};
    {
        float xt = xs[col];            // t = 0
        #pragma unroll
        for (int T = 0; T < 4; ++T) {
            cq[T][0] = fmaf(xt, wih2[T][0], bia2[T][0]);
            cq[T][1] = fmaf(xt, wih2[T][1], bia2[T][1]);
        }
    }

    const int pr = 8 * half + 2 * quad + rsel;   // h-pair index (covers j0, j0+1)

    #pragma unroll 2
    for (int t = 0; t < 512; ++t) {
        unsigned int* buf = hb[t & 1];

        f32x4 acc[4];
        #pragma unroll
        for (int T = 0; T < 4; ++T)
            acc[T] = __builtin_amdgcn_mfma_f32_16x16x32_f16(wA[T], bfrag, cq[T], 0, 0, 0);

        float xt1 = xs[((t + 1) & 511) * 17 + col];  // prefetch next x

        // activations for the 2 owned hiddens (slots 0,1) — numerics identical to R5/R6
        float ei0 = __builtin_amdgcn_exp2f(-acc[0][0]);
        float ef0 = __builtin_amdgcn_exp2f(-acc[1][0]);
        float eg0 = __builtin_amdgcn_exp2f(-acc[2][0]);
        float eo0 = __builtin_amdgcn_exp2f(-acc[3][0]);
        float ei1 = __builtin_amdgcn_exp2f(-acc[0][1]);
        float ef1 = __builtin_amdgcn_exp2f(-acc[1][1]);
        float eg1 = __builtin_amdgcn_exp2f(-acc[2][1]);
        float eo1 = __builtin_amdgcn_exp2f(-acc[3][1]);
        float si0 = __builtin_amdgcn_rcpf(1.0f + ei0);
        float sf0 = __builtin_amdgcn_rcpf(1.0f + ef0);
        float sg0 = __builtin_amdgcn_rcpf(1.0f + eg0);
        float so0 = __builtin_amdgcn_rcpf(1.0f + eo0);
        float si1 = __builtin_amdgcn_rcpf(1.0f + ei1);
        float sf1 = __builtin_amdgcn_rcpf(1.0f + ef1);
        float sg1 = __builtin_amdgcn_rcpf(1.0f + eg1);
        float so1 = __builtin_amdgcn_rcpf(1.0f + eo1);
        float gg0 = fmaf(2.0f, sg0, -1.0f);
        float gg1 = fmaf(2.0f, sg1, -1.0f);
        c0 = fmaf(sf0, c0, si0 * gg0);
        c1 = fmaf(sf1, c1, si1 * gg1);
        float tc0 = __builtin_amdgcn_rcpf(1.0f + __builtin_amdgcn_exp2f(c0 * (-2.0f * L2E)));
        float tc1 = __builtin_amdgcn_rcpf(1.0f + __builtin_amdgcn_exp2f(c1 * (-2.0f * L2E)));
        h0 = so0 * fmaf(2.0f, tc0, -1.0f);
        h1 = so1 * fmaf(2.0f, tc1, -1.0f);

        buf[col * 20 + pr] =
            __builtin_bit_cast(unsigned int, __builtin_amdgcn_cvt_pkrtz(h0, h1));

        // next step's C-init in the pre-barrier slack
        #pragma unroll
        for (int T = 0; T < 4; ++T) {
            cq[T][0] = fmaf(xt1, wih2[T][0], bia2[T][0]);
            cq[T][1] = fmaf(xt1, wih2[T][1], bia2[T][1]);
        }

        __syncthreads();
        // B-frag: pairs quad*4..+3 of batch col = k quad*8..quad*8+7
        uint4 bv = *(const uint4*)&buf[col * 20 + quad * 4];
        bfrag = __builtin_bit_cast(f16x8, bv);
    }

    // ---- epilogue: out[b] = sum_j h_j * W_lin[j] + b_lin ----
    float v = fmaf(h0, wl0, h1 * wl1);
    v += __shfl_xor(v, 16);            // combine quads
    v += __shfl_xor(v, 32);
    if (lane < 16) ps[wv * 16 + col] = v;
    __syncthreads();
    if (tid < 16)
        out[base + tid] = ps[tid] + ps[16 + tid] + ps[32 + tid] + ps[48 + tid] + b_lin[0];
}

extern "C" void kernel_launch(void* const* d_in, const int* in_sizes, int n_in,
                              void* d_out, int out_size, void* d_ws, size_t ws_size,
                              hipStream_t stream) {
    const float* x     = (const float*)d_in[0];
    const float* W_ih  = (const float*)d_in[1];
    const float* W_hh  = (const float*)d_in[2];
    const float* b_ih  = (const float*)d_in[3];
    const float* b_hh  = (const float*)d_in[4];
    const float* W_lin = (const float*)d_in[5];
    const float* b_lin = (const float*)d_in[6];
    float* out = (float*)d_out;

    const int B = in_sizes[0] / 512;   // 8192
    dim3 grid(B / 16), block(256);
    lstm_mfma4<<<grid, block, 0, stream>>>(x, W_ih, W_hh, b_ih, b_hh, W_lin, b_lin, out);
}